// Round 4
// baseline (3169.248 us; speedup 1.0000x reference)
//
#include <hip/hip_runtime.h>

#define FDIM 128

// ---------------------------------------------------------------------------
// Kernel 0: transpose W (128x128) into ws so the GEMM's LDS staging is both
// globally coalesced and LDS-bank-conflict-free.
// ---------------------------------------------------------------------------
__global__ __launch_bounds__(256) void transpose_W_kernel(
    const float* __restrict__ W, float* __restrict__ Wt)
{
    int idx = blockIdx.x * 256 + threadIdx.x;   // 0..16383
    int f = idx & 127, k = idx >> 7;
    // Wt[k][f] = W[f][k]
    Wt[k * FDIM + f] = W[f * FDIM + k];
}

// ---------------------------------------------------------------------------
// Kernel 1: h = nfeat @ W.T + b   (store h to ws)
//           out = relu(h + root_emb) / degs   (initializes d_out fully)
// 32 rows per block, 256 threads, each thread computes a 4x4 register tile.
// N = 100000 is an exact multiple of 32 -> no guards.
// ---------------------------------------------------------------------------
__global__ __launch_bounds__(256) void node_linear_kernel(
    const float* __restrict__ nfeat, const float* __restrict__ Wt,
    const float* __restrict__ bias,  const float* __restrict__ root,
    const float* __restrict__ degs,  float* __restrict__ h,
    float* __restrict__ out)
{
    __shared__ float As[32][132];   // A tile, padded: +4 keeps float4 alignment
    __shared__ float Ws[64][132];   // W^T chunk [k][f]

    const int tid  = threadIdx.x;
    const int row0 = blockIdx.x << 5;
    const int fg = tid & 31, rg = tid >> 5;
    const int f0 = fg << 2, r0 = rg << 2;

    // stage A tile: 32 rows x 128 cols, coalesced reads, conflict-free writes
    for (int i = tid; i < 32 * FDIM; i += 256) {
        int r = i >> 7, k = i & 127;
        As[r][k] = nfeat[(size_t)(row0 + r) * FDIM + k];
    }

    float acc[4][4] = {{0.f}};

    for (int kc = 0; kc < 2; ++kc) {
        const int kbase = kc << 6;
        __syncthreads();            // protect Ws from previous chunk's readers
        for (int i = tid; i < 64 * FDIM; i += 256) {
            int kk = i >> 7, f = i & 127;
            Ws[kk][f] = Wt[(size_t)(kbase + kk) * FDIM + f];
        }
        __syncthreads();

        for (int kk = 0; kk < 64; kk += 4) {
            float a[4][4], w[4][4];
#pragma unroll
            for (int j = 0; j < 4; ++j) {
                float4 v = *reinterpret_cast<const float4*>(&As[r0 + j][kbase + kk]);
                a[j][0] = v.x; a[j][1] = v.y; a[j][2] = v.z; a[j][3] = v.w;
            }
#pragma unroll
            for (int j = 0; j < 4; ++j) {
                float4 v = *reinterpret_cast<const float4*>(&Ws[kk + j][f0]);
                w[j][0] = v.x; w[j][1] = v.y; w[j][2] = v.z; w[j][3] = v.w;
            }
#pragma unroll
            for (int j = 0; j < 4; ++j)
#pragma unroll
                for (int rr = 0; rr < 4; ++rr)
#pragma unroll
                    for (int cc = 0; cc < 4; ++cc)
                        acc[rr][cc] = fmaf(a[rr][j], w[j][cc], acc[rr][cc]);
        }
    }

    float4 bv = *reinterpret_cast<const float4*>(&bias[f0]);
    float4 rv = *reinterpret_cast<const float4*>(&root[f0]);
    const float bb[4] = {bv.x, bv.y, bv.z, bv.w};
    const float rt[4] = {rv.x, rv.y, rv.z, rv.w};

#pragma unroll
    for (int rr = 0; rr < 4; ++rr) {
        int row = row0 + r0 + rr;
        float invd = 1.0f / degs[row];     // degs are small ints; error ~1 ulp
        float hv[4], ov[4];
#pragma unroll
        for (int cc = 0; cc < 4; ++cc) {
            float x = acc[rr][cc] + bb[cc];
            hv[cc] = x;
            ov[cc] = fmaxf(x + rt[cc], 0.f) * invd;
        }
        *reinterpret_cast<float4*>(&h[(size_t)row * FDIM + f0]) =
            make_float4(hv[0], hv[1], hv[2], hv[3]);
        *reinterpret_cast<float4*>(&out[(size_t)row * FDIM + f0]) =
            make_float4(ov[0], ov[1], ov[2], ov[3]);
    }
}

// ---------------------------------------------------------------------------
// Kernel 2: for each edge e:
//   emb = be + efeat[e] @ We.T          (7-term FMA, weights in registers)
//   v   = norm[e] * relu(h[src[e]] + emb)
//   out[dst[e]] += v                    (f32 hardware atomics)
// 32 threads per edge (float4 each), 8 edges per pass, 4 passes per block.
// E = 1600000 is an exact multiple of 32.
// ---------------------------------------------------------------------------
__global__ __launch_bounds__(256) void edge_scatter_kernel(
    const float* __restrict__ h,    const float* __restrict__ efeat,
    const float* __restrict__ norm, const int* __restrict__ src,
    const int* __restrict__ dst,    const float* __restrict__ We,
    const float* __restrict__ be,   float* __restrict__ out, int E)
{
    __shared__ float WeT[7][FDIM];
    __shared__ float bes[FDIM];

    const int tid = threadIdx.x;
    for (int i = tid; i < 7 * FDIM; i += 256) {
        int j = i >> 7, f = i & 127;
        WeT[j][f] = We[f * 7 + j];
    }
    if (tid < FDIM) bes[tid] = be[tid];
    __syncthreads();

    const int le = tid >> 5;              // edge lane-group 0..7
    const int f0 = (tid & 31) << 2;       // feature offset, float4 per thread

    // hoist per-thread weights out of the edge loop (28 + 4 VGPRs)
    float4 bev = *reinterpret_cast<const float4*>(&bes[f0]);
    float em0[4] = {bev.x, bev.y, bev.z, bev.w};
    float wreg[7][4];
#pragma unroll
    for (int j = 0; j < 7; ++j) {
        float4 wv = *reinterpret_cast<const float4*>(&WeT[j][f0]);
        wreg[j][0] = wv.x; wreg[j][1] = wv.y; wreg[j][2] = wv.z; wreg[j][3] = wv.w;
    }

    const size_t e0 = (size_t)blockIdx.x * 32 + le;
#pragma unroll 1
    for (int it = 0; it < 4; ++it) {
        size_t e = e0 + (size_t)it * 8;
        if (e >= (size_t)E) continue;
        int s = src[e], d = dst[e];
        float nv = norm[e];

        float em[4] = {em0[0], em0[1], em0[2], em0[3]};
#pragma unroll
        for (int j = 0; j < 7; ++j) {
            float ej = efeat[e * 7 + j];
#pragma unroll
            for (int c = 0; c < 4; ++c)
                em[c] = fmaf(ej, wreg[j][c], em[c]);
        }

        float4 hv = *reinterpret_cast<const float4*>(&h[(size_t)s * FDIM + f0]);
        const float hvv[4] = {hv.x, hv.y, hv.z, hv.w};

        float* op = &out[(size_t)d * FDIM + f0];
#pragma unroll
        for (int c = 0; c < 4; ++c) {
            float v = nv * fmaxf(hvv[c] + em[c], 0.f);
            unsafeAtomicAdd(op + c, v);   // global_atomic_add_f32
        }
    }
}

// ---------------------------------------------------------------------------
extern "C" void kernel_launch(void* const* d_in, const int* in_sizes, int n_in,
                              void* d_out, int out_size, void* d_ws, size_t ws_size,
                              hipStream_t stream)
{
    const float* nfeat = (const float*)d_in[0];
    const float* efeat = (const float*)d_in[1];
    const float* degs  = (const float*)d_in[2];
    const float* norm  = (const float*)d_in[3];
    const int*   src   = (const int*)  d_in[4];
    const int*   dst   = (const int*)  d_in[5];
    const float* W     = (const float*)d_in[6];
    const float* b     = (const float*)d_in[7];
    const float* We    = (const float*)d_in[8];
    const float* be    = (const float*)d_in[9];
    const float* root  = (const float*)d_in[10];
    float* out = (float*)d_out;

    const int N = in_sizes[0] / FDIM;   // 100000
    const int E = in_sizes[4];          // 1600000

    float* h  = (float*)d_ws;                         // N*FDIM floats (51.2 MB)
    float* Wt = h + (size_t)N * FDIM;                 // 16384 floats

    transpose_W_kernel<<<64, 256, 0, stream>>>(W, Wt);
    node_linear_kernel<<<N / 32, 256, 0, stream>>>(nfeat, Wt, b, root, degs, h, out);
    edge_scatter_kernel<<<(E + 31) / 32, 256, 0, stream>>>(
        h, efeat, norm, src, dst, We, be, out, E);
}

// Round 5
// 1200.650 us; speedup vs baseline: 2.6396x; 2.6396x over previous
//
#include <hip/hip_runtime.h>

#define FDIM 128
#define EFD  7

// ---------------------------------------------------------------------------
// Kernel 0: transpose W (128x128) into ws for conflict-free GEMM staging.
// ---------------------------------------------------------------------------
__global__ __launch_bounds__(256) void transpose_W_kernel(
    const float* __restrict__ W, float* __restrict__ Wt)
{
    int idx = blockIdx.x * 256 + threadIdx.x;   // 0..16383
    int f = idx & 127, k = idx >> 7;
    Wt[k * FDIM + f] = W[f * FDIM + k];
}

// ---------------------------------------------------------------------------
// Kernel 1: h = nfeat @ W.T + b   (store h to ws)
//           out = relu(h + root_emb) / degs   (used by the fallback path;
//           binned path overwrites out, cost is one extra 51MB stream write)
// ---------------------------------------------------------------------------
__global__ __launch_bounds__(256) void node_linear_kernel(
    const float* __restrict__ nfeat, const float* __restrict__ Wt,
    const float* __restrict__ bias,  const float* __restrict__ root,
    const float* __restrict__ degs,  float* __restrict__ h,
    float* __restrict__ out)
{
    __shared__ float As[32][132];
    __shared__ float Ws[64][132];

    const int tid  = threadIdx.x;
    const int row0 = blockIdx.x << 5;
    const int fg = tid & 31, rg = tid >> 5;
    const int f0 = fg << 2, r0 = rg << 2;

    for (int i = tid; i < 32 * FDIM; i += 256) {
        int r = i >> 7, k = i & 127;
        As[r][k] = nfeat[(size_t)(row0 + r) * FDIM + k];
    }

    float acc[4][4] = {{0.f}};

    for (int kc = 0; kc < 2; ++kc) {
        const int kbase = kc << 6;
        __syncthreads();
        for (int i = tid; i < 64 * FDIM; i += 256) {
            int kk = i >> 7, f = i & 127;
            Ws[kk][f] = Wt[(size_t)(kbase + kk) * FDIM + f];
        }
        __syncthreads();

        for (int kk = 0; kk < 64; kk += 4) {
            float a[4][4], w[4][4];
#pragma unroll
            for (int j = 0; j < 4; ++j) {
                float4 v = *reinterpret_cast<const float4*>(&As[r0 + j][kbase + kk]);
                a[j][0] = v.x; a[j][1] = v.y; a[j][2] = v.z; a[j][3] = v.w;
            }
#pragma unroll
            for (int j = 0; j < 4; ++j) {
                float4 v = *reinterpret_cast<const float4*>(&Ws[kk + j][f0]);
                w[j][0] = v.x; w[j][1] = v.y; w[j][2] = v.z; w[j][3] = v.w;
            }
#pragma unroll
            for (int j = 0; j < 4; ++j)
#pragma unroll
                for (int rr = 0; rr < 4; ++rr)
#pragma unroll
                    for (int cc = 0; cc < 4; ++cc)
                        acc[rr][cc] = fmaf(a[rr][j], w[j][cc], acc[rr][cc]);
        }
    }

    float4 bv = *reinterpret_cast<const float4*>(&bias[f0]);
    float4 rv = *reinterpret_cast<const float4*>(&root[f0]);
    const float bb[4] = {bv.x, bv.y, bv.z, bv.w};
    const float rt[4] = {rv.x, rv.y, rv.z, rv.w};

#pragma unroll
    for (int rr = 0; rr < 4; ++rr) {
        int row = row0 + r0 + rr;
        float invd = 1.0f / degs[row];
        float hv[4], ov[4];
#pragma unroll
        for (int cc = 0; cc < 4; ++cc) {
            float x = acc[rr][cc] + bb[cc];
            hv[cc] = x;
            ov[cc] = fmaxf(x + rt[cc], 0.f) * invd;
        }
        *reinterpret_cast<float4*>(&h[(size_t)row * FDIM + f0]) =
            make_float4(hv[0], hv[1], hv[2], hv[3]);
        *reinterpret_cast<float4*>(&out[(size_t)row * FDIM + f0]) =
            make_float4(ov[0], ov[1], ov[2], ov[3]);
    }
}

// ---------------------------------------------------------------------------
// Binned path: histogram of dst -> exclusive scan -> bin-fill -> per-node
// register accumulation with a single clean write (no f32 atomics).
// ---------------------------------------------------------------------------
__global__ __launch_bounds__(256) void hist_kernel(
    const int* __restrict__ dst, int* __restrict__ counts, int E)
{
    int e = blockIdx.x * 256 + threadIdx.x;
    if (e < E) atomicAdd(&counts[dst[e]], 1);   // 400KB target, L2-resident
}

__global__ __launch_bounds__(1024) void scan_kernel(
    const int* __restrict__ counts, int* __restrict__ starts,
    int* __restrict__ cursor, int N, int E)
{
    __shared__ int part[1024];
    const int t = threadIdx.x;
    const int chunk = (N + 1023) / 1024;
    const int b  = t * chunk;
    const int en = min(b + chunk, N);

    int s = 0;
    for (int i = b; i < en; ++i) s += counts[i];
    part[t] = s;
    __syncthreads();
    for (int off = 1; off < 1024; off <<= 1) {
        int v = (t >= off) ? part[t - off] : 0;
        __syncthreads();
        part[t] += v;
        __syncthreads();
    }
    int run = part[t] - s;   // exclusive prefix of this thread's chunk
    for (int i = b; i < en; ++i) {
        starts[i] = run; cursor[i] = run;
        run += counts[i];
    }
    if (t == 0) starts[N] = E;
}

__global__ __launch_bounds__(256) void fill_kernel(
    const int* __restrict__ dst, int* __restrict__ cursor,
    int* __restrict__ eid, int E)
{
    int e = blockIdx.x * 256 + threadIdx.x;
    if (e < E) {
        int pos = atomicAdd(&cursor[dst[e]], 1);
        eid[pos] = e;
    }
}

// One wave per destination node: lane handles 2 feature columns (float2).
// Per edge: broadcast loads of eid/src/norm/efeat (same addr across wave),
// coalesced 512B gather of h[src], register FMA accumulate. Next edge's
// indices are prefetched to overlap the dependent-load chain.
__global__ __launch_bounds__(256) void gather_accum_kernel(
    const float* __restrict__ h,    const float* __restrict__ efeat,
    const float* __restrict__ norm, const int* __restrict__ src,
    const int* __restrict__ eid,    const int* __restrict__ starts,
    const float* __restrict__ We,   const float* __restrict__ be,
    const float* __restrict__ root, const float* __restrict__ degs,
    float* __restrict__ out, int N)
{
    const int tid  = threadIdx.x;
    const int wave = tid >> 6, lane = tid & 63;
    const int n = blockIdx.x * 4 + wave;
    if (n >= N) return;
    const int f0 = lane << 1;

    // per-lane edge-encoder weights for 2 feature columns (once per wave)
    float2 wj[EFD];
#pragma unroll
    for (int j = 0; j < EFD; ++j) {
        wj[j].x = We[(size_t)(f0    ) * EFD + j];
        wj[j].y = We[(size_t)(f0 + 1) * EFD + j];
    }
    const float2 bev = { be[f0], be[f0 + 1] };
    const float2 rv  = { root[f0], root[f0 + 1] };

    const int s0 = starts[n], s1 = starts[n + 1];
    float2 acc = {0.f, 0.f};

    int e = 0, s = 0; float nv = 0.f;
    if (s0 < s1) { e = eid[s0]; s = src[e]; nv = norm[e]; }

    for (int i = s0; i < s1; ++i) {
        float ef[EFD];
#pragma unroll
        for (int j = 0; j < EFD; ++j) ef[j] = efeat[(size_t)e * EFD + j];
        float2 hv = *reinterpret_cast<const float2*>(&h[(size_t)s * FDIM + f0]);

        // prefetch next edge's indirection chain before consuming hv
        int e2 = 0, s2 = 0; float nv2 = 0.f;
        if (i + 1 < s1) { e2 = eid[i + 1]; s2 = src[e2]; nv2 = norm[e2]; }

        float2 em = bev;
#pragma unroll
        for (int j = 0; j < EFD; ++j) {
            em.x = fmaf(ef[j], wj[j].x, em.x);
            em.y = fmaf(ef[j], wj[j].y, em.y);
        }
        acc.x = fmaf(nv, fmaxf(hv.x + em.x, 0.f), acc.x);
        acc.y = fmaf(nv, fmaxf(hv.y + em.y, 0.f), acc.y);

        e = e2; s = s2; nv = nv2;
    }

    float2 hn = *reinterpret_cast<const float2*>(&h[(size_t)n * FDIM + f0]);
    const float invd = 1.0f / degs[n];
    float2 o;
    o.x = acc.x + fmaxf(hn.x + rv.x, 0.f) * invd;
    o.y = acc.y + fmaxf(hn.y + rv.y, 0.f) * invd;
    *reinterpret_cast<float2*>(&out[(size_t)n * FDIM + f0]) = o;
}

// ---------------------------------------------------------------------------
// Fallback (proven round-4 path): f32 atomics, used only if ws too small.
// ---------------------------------------------------------------------------
__global__ __launch_bounds__(256) void edge_scatter_kernel(
    const float* __restrict__ h,    const float* __restrict__ efeat,
    const float* __restrict__ norm, const int* __restrict__ src,
    const int* __restrict__ dst,    const float* __restrict__ We,
    const float* __restrict__ be,   float* __restrict__ out, int E)
{
    __shared__ float WeT[EFD][FDIM];
    __shared__ float bes[FDIM];

    const int tid = threadIdx.x;
    for (int i = tid; i < EFD * FDIM; i += 256) {
        int j = i >> 7, f = i & 127;
        WeT[j][f] = We[f * EFD + j];
    }
    if (tid < FDIM) bes[tid] = be[tid];
    __syncthreads();

    const int le = tid >> 5;
    const int f0 = (tid & 31) << 2;

    float4 bev = *reinterpret_cast<const float4*>(&bes[f0]);
    float em0[4] = {bev.x, bev.y, bev.z, bev.w};
    float wreg[EFD][4];
#pragma unroll
    for (int j = 0; j < EFD; ++j) {
        float4 wv = *reinterpret_cast<const float4*>(&WeT[j][f0]);
        wreg[j][0] = wv.x; wreg[j][1] = wv.y; wreg[j][2] = wv.z; wreg[j][3] = wv.w;
    }

    const size_t e0 = (size_t)blockIdx.x * 32 + le;
#pragma unroll 1
    for (int it = 0; it < 4; ++it) {
        size_t e = e0 + (size_t)it * 8;
        if (e >= (size_t)E) continue;
        int s = src[e], d = dst[e];
        float nv = norm[e];

        float em[4] = {em0[0], em0[1], em0[2], em0[3]};
#pragma unroll
        for (int j = 0; j < EFD; ++j) {
            float ej = efeat[e * EFD + j];
#pragma unroll
            for (int c = 0; c < 4; ++c)
                em[c] = fmaf(ej, wreg[j][c], em[c]);
        }

        float4 hv = *reinterpret_cast<const float4*>(&h[(size_t)s * FDIM + f0]);
        const float hvv[4] = {hv.x, hv.y, hv.z, hv.w};

        float* op = &out[(size_t)d * FDIM + f0];
#pragma unroll
        for (int c = 0; c < 4; ++c) {
            float v = nv * fmaxf(hvv[c] + em[c], 0.f);
            unsafeAtomicAdd(op + c, v);
        }
    }
}

// ---------------------------------------------------------------------------
extern "C" void kernel_launch(void* const* d_in, const int* in_sizes, int n_in,
                              void* d_out, int out_size, void* d_ws, size_t ws_size,
                              hipStream_t stream)
{
    const float* nfeat = (const float*)d_in[0];
    const float* efeat = (const float*)d_in[1];
    const float* degs  = (const float*)d_in[2];
    const float* norm  = (const float*)d_in[3];
    const int*   src   = (const int*)  d_in[4];
    const int*   dst   = (const int*)  d_in[5];
    const float* W     = (const float*)d_in[6];
    const float* b     = (const float*)d_in[7];
    const float* We    = (const float*)d_in[8];
    const float* be    = (const float*)d_in[9];
    const float* root  = (const float*)d_in[10];
    float* out = (float*)d_out;

    const int N = in_sizes[0] / FDIM;   // 100000
    const int E = in_sizes[4];          // 1600000

    char* ws = (char*)d_ws;
    size_t off = 0;
    float* h      = (float*)(ws + off); off += (size_t)N * FDIM * 4;
    float* Wt     = (float*)(ws + off); off += (size_t)FDIM * FDIM * 4;
    int*   eid    = (int*)  (ws + off); off += (size_t)E * 4;
    int*   counts = (int*)  (ws + off); off += (size_t)N * 4;
    int*   starts = (int*)  (ws + off); off += (size_t)(N + 1) * 4;
    int*   cursor = (int*)  (ws + off); off += (size_t)N * 4;
    const bool binned = (ws_size >= off);   // constant across calls

    transpose_W_kernel<<<64, 256, 0, stream>>>(W, Wt);
    node_linear_kernel<<<N / 32, 256, 0, stream>>>(nfeat, Wt, b, root, degs, h, out);

    if (binned) {
        hipMemsetAsync(counts, 0, (size_t)N * 4, stream);
        hist_kernel<<<(E + 255) / 256, 256, 0, stream>>>(dst, counts, E);
        scan_kernel<<<1, 1024, 0, stream>>>(counts, starts, cursor, N, E);
        fill_kernel<<<(E + 255) / 256, 256, 0, stream>>>(dst, cursor, eid, E);
        gather_accum_kernel<<<(N + 3) / 4, 256, 0, stream>>>(
            h, efeat, norm, src, eid, starts, We, be, root, degs, out, N);
    } else {
        edge_scatter_kernel<<<(E + 31) / 32, 256, 0, stream>>>(
            h, efeat, norm, src, dst, We, be, out, E);
    }
}

// Round 8
// 824.859 us; speedup vs baseline: 3.8422x; 1.4556x over previous
//
#include <hip/hip_runtime.h>

#define FDIM 128
#define EFD  7

// ---------------------------------------------------------------------------
// Kernel 0: transpose W (128x128) -> Wt[k][f] so GEMM reads are coalesced.
// ---------------------------------------------------------------------------
__global__ __launch_bounds__(256) void transpose_W_kernel(
    const float* __restrict__ W, float* __restrict__ Wt)
{
    int idx = blockIdx.x * 256 + threadIdx.x;   // 0..16383
    int f = idx & 127, k = idx >> 7;
    Wt[k * FDIM + f] = W[f * FDIM + k];
}

// ---------------------------------------------------------------------------
// Kernel 1 (Design B): h = nfeat @ W.T + b; optionally out = relu(h+root)/degs.
// LDS holds only the 32x128 A-tile (17 KB). Wt rows are read straight from
// global: within a block every wave reads the same 2 KB row-group per k-step,
// so after the leader miss they are L1-hits. k-loop kept rolled
// (#pragma unroll 1) to hold live registers at ~60 (round-5 version hit 256
// VGPR / 10% occupancy / spill traffic).
// ---------------------------------------------------------------------------
__global__ __launch_bounds__(256) void node_linear_kernel(
    const float* __restrict__ nfeat, const float* __restrict__ Wt,
    const float* __restrict__ bias,  const float* __restrict__ root,
    const float* __restrict__ degs,  float* __restrict__ h,
    float* __restrict__ out, int write_out)
{
    __shared__ float As[32][132];   // +4 pad: float4-aligned, conflict-free

    const int tid  = threadIdx.x;
    const int row0 = blockIdx.x << 5;
    const int fg = tid & 31, rg = tid >> 5;
    const int f0 = fg << 2, r0 = rg << 2;

    // stage A tile: 1024 float4s, 4 per thread, coalesced
    {
        int i = tid;
#pragma unroll
        for (int it = 0; it < 4; ++it, i += 256) {
            int r = i >> 5, c = (i & 31) << 2;
            float4 v = *reinterpret_cast<const float4*>(
                &nfeat[(size_t)(row0 + r) * FDIM + c]);
            *reinterpret_cast<float4*>(&As[r][c]) = v;
        }
    }
    __syncthreads();

    float acc[4][4] = {{0.f}};

#pragma unroll 1
    for (int k = 0; k < FDIM; k += 4) {
        float w[4][4], a[4][4];
#pragma unroll
        for (int j = 0; j < 4; ++j) {
            float4 v = *reinterpret_cast<const float4*>(
                &Wt[(size_t)(k + j) * FDIM + f0]);
            w[j][0] = v.x; w[j][1] = v.y; w[j][2] = v.z; w[j][3] = v.w;
        }
#pragma unroll
        for (int rr = 0; rr < 4; ++rr) {
            float4 v = *reinterpret_cast<const float4*>(&As[r0 + rr][k]);
            a[rr][0] = v.x; a[rr][1] = v.y; a[rr][2] = v.z; a[rr][3] = v.w;
        }
#pragma unroll
        for (int j = 0; j < 4; ++j)
#pragma unroll
            for (int rr = 0; rr < 4; ++rr)
#pragma unroll
                for (int cc = 0; cc < 4; ++cc)
                    acc[rr][cc] = fmaf(a[rr][j], w[j][cc], acc[rr][cc]);
    }

    float4 bv = *reinterpret_cast<const float4*>(&bias[f0]);
    const float bb[4] = {bv.x, bv.y, bv.z, bv.w};

    if (write_out) {
        float4 rv = *reinterpret_cast<const float4*>(&root[f0]);
        const float rt[4] = {rv.x, rv.y, rv.z, rv.w};
#pragma unroll
        for (int rr = 0; rr < 4; ++rr) {
            int row = row0 + r0 + rr;
            float invd = 1.0f / degs[row];
            float hv[4], ov[4];
#pragma unroll
            for (int cc = 0; cc < 4; ++cc) {
                float x = acc[rr][cc] + bb[cc];
                hv[cc] = x;
                ov[cc] = fmaxf(x + rt[cc], 0.f) * invd;
            }
            *reinterpret_cast<float4*>(&h[(size_t)row * FDIM + f0]) =
                make_float4(hv[0], hv[1], hv[2], hv[3]);
            *reinterpret_cast<float4*>(&out[(size_t)row * FDIM + f0]) =
                make_float4(ov[0], ov[1], ov[2], ov[3]);
        }
    } else {
#pragma unroll
        for (int rr = 0; rr < 4; ++rr) {
            int row = row0 + r0 + rr;
            *reinterpret_cast<float4*>(&h[(size_t)row * FDIM + f0]) =
                make_float4(acc[rr][0] + bb[0], acc[rr][1] + bb[1],
                            acc[rr][2] + bb[2], acc[rr][3] + bb[3]);
        }
    }
}

// ---------------------------------------------------------------------------
// Binned path: histogram -> scan -> fill(permute) -> per-node accumulate.
// ---------------------------------------------------------------------------
__global__ __launch_bounds__(256) void hist_kernel(
    const int* __restrict__ dst, int* __restrict__ counts, int E)
{
    int e = blockIdx.x * 256 + threadIdx.x;
    if (e < E) atomicAdd(&counts[dst[e]], 1);
}

__global__ __launch_bounds__(1024) void scan_kernel(
    const int* __restrict__ counts, int* __restrict__ starts,
    int* __restrict__ cursor, int N, int E)
{
    __shared__ int part[1024];
    const int t = threadIdx.x;
    const int chunk = (N + 1023) / 1024;
    const int b  = t * chunk;
    const int en = min(b + chunk, N);

    int s = 0;
    for (int i = b; i < en; ++i) s += counts[i];
    part[t] = s;
    __syncthreads();
    for (int off = 1; off < 1024; off <<= 1) {
        int v = (t >= off) ? part[t - off] : 0;
        __syncthreads();
        part[t] += v;
        __syncthreads();
    }
    int run = part[t] - s;
    for (int i = b; i < en; ++i) {
        starts[i] = run; cursor[i] = run;
        run += counts[i];
    }
    if (t == 0) starts[N] = E;
}

// T1 fill: permute src/norm/efeat into dst-sorted order (pad efeat to 8 f32)
__global__ __launch_bounds__(256) void fill_packed_kernel(
    const int* __restrict__ dst,  const int* __restrict__ src,
    const float* __restrict__ norm, const float* __restrict__ efeat,
    int* __restrict__ cursor, int* __restrict__ srcn,
    float* __restrict__ normp, float* __restrict__ ef8, int E)
{
    int e = blockIdx.x * 256 + threadIdx.x;
    if (e < E) {
        int pos = atomicAdd(&cursor[dst[e]], 1);
        srcn[pos]  = src[e];
        normp[pos] = norm[e];
        const float* ep = &efeat[(size_t)e * EFD];
        float4 v1 = make_float4(ep[0], ep[1], ep[2], ep[3]);
        float4 v2 = make_float4(ep[4], ep[5], ep[6], 0.f);
        *reinterpret_cast<float4*>(&ef8[(size_t)pos * 8])     = v1;
        *reinterpret_cast<float4*>(&ef8[(size_t)pos * 8 + 4]) = v2;
    }
}

// T2 fill: edge-id permutation only (round-5 proven path)
__global__ __launch_bounds__(256) void fill_kernel(
    const int* __restrict__ dst, int* __restrict__ cursor,
    int* __restrict__ eid, int E)
{
    int e = blockIdx.x * 256 + threadIdx.x;
    if (e < E) {
        int pos = atomicAdd(&cursor[dst[e]], 1);
        eid[pos] = e;
    }
}

// T1 gather: one wave per node; all meta reads sequential (pre-permuted),
// only h[src] is a gather. 2-edge software pipeline keeps one extra h-load
// in flight.
__global__ __launch_bounds__(256) void gather_packed_kernel(
    const float* __restrict__ h,    const int* __restrict__ srcn,
    const float* __restrict__ normp, const float* __restrict__ ef8,
    const int* __restrict__ starts, const float* __restrict__ We,
    const float* __restrict__ be,   const float* __restrict__ root,
    const float* __restrict__ degs, float* __restrict__ out, int N)
{
    const int tid  = threadIdx.x;
    const int wave = tid >> 6, lane = tid & 63;
    const int n = blockIdx.x * 4 + wave;
    if (n >= N) return;
    const int f0 = lane << 1;

    float2 wj[EFD];
#pragma unroll
    for (int j = 0; j < EFD; ++j) {
        wj[j].x = We[(size_t)(f0    ) * EFD + j];
        wj[j].y = We[(size_t)(f0 + 1) * EFD + j];
    }
    const float2 bev = { be[f0], be[f0 + 1] };
    const float2 rv  = { root[f0], root[f0 + 1] };

    const int s0 = starts[n], s1 = starts[n + 1];
    float2 acc = {0.f, 0.f};

    int   sA = 0; float nvA = 0.f;
    float4 eA1 = {0,0,0,0}, eA2 = {0,0,0,0};
    float2 hvA = {0.f, 0.f};
    if (s0 < s1) {
        sA  = srcn[s0]; nvA = normp[s0];
        eA1 = *reinterpret_cast<const float4*>(&ef8[(size_t)s0 * 8]);
        eA2 = *reinterpret_cast<const float4*>(&ef8[(size_t)s0 * 8 + 4]);
        hvA = *reinterpret_cast<const float2*>(&h[(size_t)sA * FDIM + f0]);
    }

    for (int i = s0; i < s1; ++i) {
        int   sB = 0; float nvB = 0.f;
        float4 eB1 = {0,0,0,0}, eB2 = {0,0,0,0};
        float2 hvB = {0.f, 0.f};
        int ip = i + 1;
        if (ip < s1) {
            sB  = srcn[ip]; nvB = normp[ip];
            eB1 = *reinterpret_cast<const float4*>(&ef8[(size_t)ip * 8]);
            eB2 = *reinterpret_cast<const float4*>(&ef8[(size_t)ip * 8 + 4]);
            hvB = *reinterpret_cast<const float2*>(&h[(size_t)sB * FDIM + f0]);
        }

        const float ef[EFD] = {eA1.x, eA1.y, eA1.z, eA1.w, eA2.x, eA2.y, eA2.z};
        float2 em = bev;
#pragma unroll
        for (int j = 0; j < EFD; ++j) {
            em.x = fmaf(ef[j], wj[j].x, em.x);
            em.y = fmaf(ef[j], wj[j].y, em.y);
        }
        acc.x = fmaf(nvA, fmaxf(hvA.x + em.x, 0.f), acc.x);
        acc.y = fmaf(nvA, fmaxf(hvA.y + em.y, 0.f), acc.y);

        sA = sB; nvA = nvB; eA1 = eB1; eA2 = eB2; hvA = hvB;
    }

    float2 hn = *reinterpret_cast<const float2*>(&h[(size_t)n * FDIM + f0]);
    const float invd = 1.0f / degs[n];
    float2 o;
    o.x = acc.x + fmaxf(hn.x + rv.x, 0.f) * invd;
    o.y = acc.y + fmaxf(hn.y + rv.y, 0.f) * invd;
    *reinterpret_cast<float2*>(&out[(size_t)n * FDIM + f0]) = o;
}

// T2 gather (round-5 proven): eid indirection
__global__ __launch_bounds__(256) void gather_accum_kernel(
    const float* __restrict__ h,    const float* __restrict__ efeat,
    const float* __restrict__ norm, const int* __restrict__ src,
    const int* __restrict__ eid,    const int* __restrict__ starts,
    const float* __restrict__ We,   const float* __restrict__ be,
    const float* __restrict__ root, const float* __restrict__ degs,
    float* __restrict__ out, int N)
{
    const int tid  = threadIdx.x;
    const int wave = tid >> 6, lane = tid & 63;
    const int n = blockIdx.x * 4 + wave;
    if (n >= N) return;
    const int f0 = lane << 1;

    float2 wj[EFD];
#pragma unroll
    for (int j = 0; j < EFD; ++j) {
        wj[j].x = We[(size_t)(f0    ) * EFD + j];
        wj[j].y = We[(size_t)(f0 + 1) * EFD + j];
    }
    const float2 bev = { be[f0], be[f0 + 1] };
    const float2 rv  = { root[f0], root[f0 + 1] };

    const int s0 = starts[n], s1 = starts[n + 1];
    float2 acc = {0.f, 0.f};

    int e = 0, s = 0; float nv = 0.f;
    if (s0 < s1) { e = eid[s0]; s = src[e]; nv = norm[e]; }

    for (int i = s0; i < s1; ++i) {
        float ef[EFD];
#pragma unroll
        for (int j = 0; j < EFD; ++j) ef[j] = efeat[(size_t)e * EFD + j];
        float2 hv = *reinterpret_cast<const float2*>(&h[(size_t)s * FDIM + f0]);

        int e2 = 0, s2 = 0; float nv2 = 0.f;
        if (i + 1 < s1) { e2 = eid[i + 1]; s2 = src[e2]; nv2 = norm[e2]; }

        float2 em = bev;
#pragma unroll
        for (int j = 0; j < EFD; ++j) {
            em.x = fmaf(ef[j], wj[j].x, em.x);
            em.y = fmaf(ef[j], wj[j].y, em.y);
        }
        acc.x = fmaf(nv, fmaxf(hv.x + em.x, 0.f), acc.x);
        acc.y = fmaf(nv, fmaxf(hv.y + em.y, 0.f), acc.y);

        e = e2; s = s2; nv = nv2;
    }

    float2 hn = *reinterpret_cast<const float2*>(&h[(size_t)n * FDIM + f0]);
    const float invd = 1.0f / degs[n];
    float2 o;
    o.x = acc.x + fmaxf(hn.x + rv.x, 0.f) * invd;
    o.y = acc.y + fmaxf(hn.y + rv.y, 0.f) * invd;
    *reinterpret_cast<float2*>(&out[(size_t)n * FDIM + f0]) = o;
}

// ---------------------------------------------------------------------------
// T3 fallback: f32 atomics (round-4 proven), only if ws too small.
// ---------------------------------------------------------------------------
__global__ __launch_bounds__(256) void edge_scatter_kernel(
    const float* __restrict__ h,    const float* __restrict__ efeat,
    const float* __restrict__ norm, const int* __restrict__ src,
    const int* __restrict__ dst,    const float* __restrict__ We,
    const float* __restrict__ be,   float* __restrict__ out, int E)
{
    __shared__ float WeT[EFD][FDIM];
    __shared__ float bes[FDIM];

    const int tid = threadIdx.x;
    for (int i = tid; i < EFD * FDIM; i += 256) {
        int j = i >> 7, f = i & 127;
        WeT[j][f] = We[f * EFD + j];
    }
    if (tid < FDIM) bes[tid] = be[tid];
    __syncthreads();

    const int le = tid >> 5;
    const int f0 = (tid & 31) << 2;

    float4 bev = *reinterpret_cast<const float4*>(&bes[f0]);
    float em0[4] = {bev.x, bev.y, bev.z, bev.w};
    float wreg[EFD][4];
#pragma unroll
    for (int j = 0; j < EFD; ++j) {
        float4 wv = *reinterpret_cast<const float4*>(&WeT[j][f0]);
        wreg[j][0] = wv.x; wreg[j][1] = wv.y; wreg[j][2] = wv.z; wreg[j][3] = wv.w;
    }

    const size_t e0 = (size_t)blockIdx.x * 32 + le;
#pragma unroll 1
    for (int it = 0; it < 4; ++it) {
        size_t e = e0 + (size_t)it * 8;
        if (e >= (size_t)E) continue;
        int s = src[e], d = dst[e];
        float nv = norm[e];

        float em[4] = {em0[0], em0[1], em0[2], em0[3]};
#pragma unroll
        for (int j = 0; j < EFD; ++j) {
            float ej = efeat[e * EFD + j];
#pragma unroll
            for (int c = 0; c < 4; ++c)
                em[c] = fmaf(ej, wreg[j][c], em[c]);
        }

        float4 hv = *reinterpret_cast<const float4*>(&h[(size_t)s * FDIM + f0]);
        const float hvv[4] = {hv.x, hv.y, hv.z, hv.w};

        float* op = &out[(size_t)d * FDIM + f0];
#pragma unroll
        for (int c = 0; c < 4; ++c) {
            float v = nv * fmaxf(hvv[c] + em[c], 0.f);
            unsafeAtomicAdd(op + c, v);
        }
    }
}

// ---------------------------------------------------------------------------
extern "C" void kernel_launch(void* const* d_in, const int* in_sizes, int n_in,
                              void* d_out, int out_size, void* d_ws, size_t ws_size,
                              hipStream_t stream)
{
    const float* nfeat = (const float*)d_in[0];
    const float* efeat = (const float*)d_in[1];
    const float* degs  = (const float*)d_in[2];
    const float* norm  = (const float*)d_in[3];
    const int*   src   = (const int*)  d_in[4];
    const int*   dst   = (const int*)  d_in[5];
    const float* W     = (const float*)d_in[6];
    const float* b     = (const float*)d_in[7];
    const float* We    = (const float*)d_in[8];
    const float* be    = (const float*)d_in[9];
    const float* root  = (const float*)d_in[10];
    float* out = (float*)d_out;

    const int N = in_sizes[0] / FDIM;   // 100000
    const int E = in_sizes[4];          // 1600000

    char* ws = (char*)d_ws;
    size_t off = 0;
    float* h      = (float*)(ws + off); off += (size_t)N * FDIM * 4;
    float* Wt     = (float*)(ws + off); off += (size_t)FDIM * FDIM * 4;
    int*   counts = (int*)  (ws + off); off += (size_t)N * 4;
    int*   starts = (int*)  (ws + off); off += (size_t)(N + 1) * 4;
    int*   cursor = (int*)  (ws + off); off += (size_t)N * 4;
    const size_t common = off;

    // T1: packed permutation (srcn + normp + ef8)
    int*   srcn  = (int*)  (ws + common);
    float* normp = (float*)(ws + common + (size_t)E * 4);
    float* ef8   = (float*)(ws + common + (size_t)E * 8);
    const size_t need_t1 = common + (size_t)E * 8 + (size_t)E * 32;
    // T2: eid only
    int*   eid   = (int*)  (ws + common);
    const size_t need_t2 = common + (size_t)E * 4;

    const int tier = (ws_size >= need_t1) ? 1 : (ws_size >= need_t2) ? 2 : 3;

    transpose_W_kernel<<<64, 256, 0, stream>>>(W, Wt);
    node_linear_kernel<<<N / 32, 256, 0, stream>>>(
        nfeat, Wt, b, root, degs, h, out, tier == 3 ? 1 : 0);

    if (tier != 3) {
        hipMemsetAsync(counts, 0, (size_t)N * 4, stream);
        hist_kernel<<<(E + 255) / 256, 256, 0, stream>>>(dst, counts, E);
        scan_kernel<<<1, 1024, 0, stream>>>(counts, starts, cursor, N, E);
        if (tier == 1) {
            fill_packed_kernel<<<(E + 255) / 256, 256, 0, stream>>>(
                dst, src, norm, efeat, cursor, srcn, normp, ef8, E);
            gather_packed_kernel<<<(N + 3) / 4, 256, 0, stream>>>(
                h, srcn, normp, ef8, starts, We, be, root, degs, out, N);
        } else {
            fill_kernel<<<(E + 255) / 256, 256, 0, stream>>>(dst, cursor, eid, E);
            gather_accum_kernel<<<(N + 3) / 4, 256, 0, stream>>>(
                h, efeat, norm, src, eid, starts, We, be, root, degs, out, N);
        }
    } else {
        edge_scatter_kernel<<<(E + 31) / 32, 256, 0, stream>>>(
            h, efeat, norm, src, dst, We, be, out, E);
    }
}